// Round 14
// baseline (2744.332 us; speedup 1.0000x reference)
//
#include <hip/hip_runtime.h>
#include <hip/hip_fp16.h>

#define B 32
#define S 512
#define E 512
#define H 512
#define NH 8
#define HD 64
#define POISON 0x7FC0DEADu

typedef _Float16 h16x8 __attribute__((ext_vector_type(8)));
typedef _Float16 h16x4 __attribute__((ext_vector_type(4)));
typedef _Float16 h16x2 __attribute__((ext_vector_type(2)));
typedef float f32x4 __attribute__((ext_vector_type(4)));

#if __has_builtin(__builtin_amdgcn_fdot2)
__device__ __forceinline__ float dot2f(h16x2 a, h16x2 b, float c) {
    return __builtin_amdgcn_fdot2(a, b, c, false);
}
#else
__device__ __forceinline__ float dot2f(h16x2 a, h16x2 b, float c) {
    return c + (float)a[0] * (float)b[0] + (float)a[1] * (float)b[1];
}
#endif

__device__ __forceinline__ h16x2 pr(h16x8 v, int q) {
    h16x2 r; r[0] = v[2 * q]; r[1] = v[2 * q + 1]; return r;
}
__device__ __forceinline__ h16x2 asp(unsigned u) {
    return __builtin_bit_cast(h16x2, u);
}
__device__ __forceinline__ unsigned pack2(float x, float y) {
    unsigned short a = __builtin_bit_cast(unsigned short, (_Float16)x);
    unsigned short b = __builtin_bit_cast(unsigned short, (_Float16)y);
    return ((unsigned)b << 16) | (unsigned)a;
}

// ---------------- fp32 -> fp16 cast (vectorized, grid-stride) ----------------
__global__ __launch_bounds__(256) void cast_h(const float* __restrict__ src,
                                              _Float16* __restrict__ dst, int n4) {
    int i = blockIdx.x * 256 + threadIdx.x;
    const int stride = gridDim.x * 256;
    for (; i < n4; i += stride) {
        float4 v = ((const float4*)src)[i];
        h16x4 o;
        o[0] = (_Float16)v.x; o[1] = (_Float16)v.y;
        o[2] = (_Float16)v.z; o[3] = (_Float16)v.w;
        ((h16x4*)dst)[i] = o;
    }
}

// ---------------- MFMA GEMM: C[M,N] = A[M,K] @ W[N,K]^T + bias ----------------
// OMODE 0: f32 row-major. 1: f16 row-major. 2: f16 scattered to Vt[(b*8+h)*64+d][s].
// 3: f32 time-major scatter row r=b*512+s -> C[(s*32+b)*N+c].
template <int OMODE>
__global__ __launch_bounds__(256) void gemm_mfma(const _Float16* __restrict__ A,
                                                 const _Float16* __restrict__ W,
                                                 const float* __restrict__ bias,
                                                 void* __restrict__ Cout,
                                                 int M, int N, int K) {
    __shared__ __align__(16) _Float16 Als[128 * 32];
    __shared__ __align__(16) _Float16 Bls[128 * 32];
    const int tid = threadIdx.x;
    const int m0 = blockIdx.y * 128;
    const int n0 = blockIdx.x * 128;
    const int lane = tid & 63;
    const int w = tid >> 6;
    const int wm = w >> 1, wn = w & 1;
    f32x4 acc[4][4] = {};

    const int srow = tid >> 1;
    const int shalf = tid & 1;
    const _Float16* Ag = A + (size_t)(m0 + srow) * K + shalf * 16;
    const _Float16* Wg = W + (size_t)(n0 + srow) * K + shalf * 16;

    for (int k0 = 0; k0 < K; k0 += 32) {
        h16x8 a0 = *(const h16x8*)(Ag + k0);
        h16x8 a1 = *(const h16x8*)(Ag + k0 + 8);
        h16x8 b0 = *(const h16x8*)(Wg + k0);
        h16x8 b1 = *(const h16x8*)(Wg + k0 + 8);
        __syncthreads();
        *(h16x8*)&Als[srow * 32 + shalf * 16] = a0;
        *(h16x8*)&Als[srow * 32 + shalf * 16 + 8] = a1;
        *(h16x8*)&Bls[srow * 32 + shalf * 16] = b0;
        *(h16x8*)&Bls[srow * 32 + shalf * 16 + 8] = b1;
        __syncthreads();
        h16x8 af[4], bf[4];
#pragma unroll
        for (int mt = 0; mt < 4; ++mt)
            af[mt] = *(const h16x8*)&Als[(wm * 64 + mt * 16 + (lane & 15)) * 32 + (lane >> 4) * 8];
#pragma unroll
        for (int nt = 0; nt < 4; ++nt)
            bf[nt] = *(const h16x8*)&Bls[(wn * 64 + nt * 16 + (lane & 15)) * 32 + (lane >> 4) * 8];
#pragma unroll
        for (int mt = 0; mt < 4; ++mt)
#pragma unroll
            for (int nt = 0; nt < 4; ++nt)
                acc[mt][nt] = __builtin_amdgcn_mfma_f32_16x16x32_f16(af[mt], bf[nt], acc[mt][nt], 0, 0, 0);
    }

    float* Cf = (float*)Cout;
    _Float16* Ch = (_Float16*)Cout;
    const int colb = n0 + wn * 64 + (lane & 15);
    const int rowb = m0 + wm * 64 + ((lane >> 4) << 2);
#pragma unroll
    for (int mt = 0; mt < 4; ++mt) {
#pragma unroll
        for (int nt = 0; nt < 4; ++nt) {
            const int c = colb + nt * 16;
            const float bv = bias[c];
            if (OMODE == 2) {
                const int R0 = rowb + mt * 16;
                const int bb = R0 >> 9, s = R0 & 511, hh = c >> 6, d = c & 63;
                h16x4 pk;
#pragma unroll
                for (int j = 0; j < 4; ++j) pk[j] = (_Float16)(acc[mt][nt][j] + bv);
                *(h16x4*)&Ch[((size_t)(bb * 8 + hh) * 64 + d) * 512 + s] = pk;
            } else {
#pragma unroll
                for (int j = 0; j < 4; ++j) {
                    const int R = rowb + mt * 16 + j;
                    const float v = acc[mt][nt][j] + bv;
                    if (OMODE == 0) Cf[(size_t)R * N + c] = v;
                    else if (OMODE == 3) Cf[((size_t)(R & 511) * 32 + (R >> 9)) * N + c] = v;
                    else Ch[(size_t)R * N + c] = (_Float16)v;
                }
            }
        }
    }
}

// ---------------- MFMA flash attention: per (b, h, 64-row q-tile) ----------------
__global__ __launch_bounds__(256) void attn_mfma(_Float16* __restrict__ Qb,
                                                 const _Float16* __restrict__ Kb,
                                                 const _Float16* __restrict__ Vt) {
    __shared__ __align__(16) _Float16 Qs[64 * 72];
    __shared__ __align__(16) _Float16 Ks[64 * 72];
    __shared__ __align__(16) _Float16 Vs[64 * 72];
    __shared__ __align__(16) _Float16 Ps[4 * 16 * 72];
    const int tid = threadIdx.x;
    const int lane = tid & 63;
    const int w = tid >> 6;
    const int qt = blockIdx.x & 7;
    const int h = (blockIdx.x >> 3) & 7;
    const int b = blockIdx.x >> 6;
    const size_t qrow0 = (size_t)b * 512 + qt * 64;
    const int col0 = h * 64;

    {
        const int r = tid >> 2;
        const int c0 = (tid & 3) << 4;
        const _Float16* gq = &Qb[(qrow0 + r) * 512 + col0 + c0];
        *(h16x8*)&Qs[r * 72 + c0] = *(const h16x8*)(gq);
        *(h16x8*)&Qs[r * 72 + c0 + 8] = *(const h16x8*)(gq + 8);
    }
    __syncthreads();
    h16x8 aq[2];
#pragma unroll
    for (int ks = 0; ks < 2; ++ks)
        aq[ks] = *(const h16x8*)&Qs[(w * 16 + (lane & 15)) * 72 + ks * 32 + (lane >> 4) * 8];

    float m[4] = {-1e30f, -1e30f, -1e30f, -1e30f};
    float l[4] = {0.f, 0.f, 0.f, 0.f};
    f32x4 acco[4] = {};

    for (int kt = 0; kt < 8; ++kt) {
        __syncthreads();
        {
            const int r = tid >> 2;
            const int c0 = (tid & 3) << 4;
            const _Float16* gk = &Kb[((size_t)b * 512 + kt * 64 + r) * 512 + col0 + c0];
            *(h16x8*)&Ks[r * 72 + c0] = *(const h16x8*)(gk);
            *(h16x8*)&Ks[r * 72 + c0 + 8] = *(const h16x8*)(gk + 8);
            const _Float16* gv = &Vt[((size_t)(b * 8 + h) * 64 + r) * 512 + kt * 64 + c0];
            *(h16x8*)&Vs[r * 72 + c0] = *(const h16x8*)(gv);
            *(h16x8*)&Vs[r * 72 + c0 + 8] = *(const h16x8*)(gv + 8);
        }
        __syncthreads();
        f32x4 accs[4] = {};
#pragma unroll
        for (int nt = 0; nt < 4; ++nt) {
#pragma unroll
            for (int ks = 0; ks < 2; ++ks) {
                h16x8 bk = *(const h16x8*)&Ks[(nt * 16 + (lane & 15)) * 72 + ks * 32 + (lane >> 4) * 8];
                accs[nt] = __builtin_amdgcn_mfma_f32_16x16x32_f16(aq[ks], bk, accs[nt], 0, 0, 0);
            }
        }
#pragma unroll
        for (int j = 0; j < 4; ++j) {
            float v = fmaxf(fmaxf(accs[0][j], accs[1][j]), fmaxf(accs[2][j], accs[3][j]));
#pragma unroll
            for (int o = 1; o < 16; o <<= 1) v = fmaxf(v, __shfl_xor(v, o, 64));
            const float mn = fmaxf(m[j], v);
            const float scl = __expf(0.125f * (m[j] - mn));
            m[j] = mn;
            l[j] *= scl;
#pragma unroll
            for (int nt2 = 0; nt2 < 4; ++nt2) acco[nt2][j] *= scl;
            float ps = 0.f;
            const int prow = ((lane >> 4) << 2) + j;
#pragma unroll
            for (int nt = 0; nt < 4; ++nt) {
                const float p = __expf(0.125f * (accs[nt][j] - mn));
                ps += p;
                Ps[w * 16 * 72 + prow * 72 + nt * 16 + (lane & 15)] = (_Float16)p;
            }
#pragma unroll
            for (int o = 1; o < 16; o <<= 1) ps += __shfl_xor(ps, o, 64);
            l[j] += ps;
        }
        __syncthreads();
#pragma unroll
        for (int ks2 = 0; ks2 < 2; ++ks2) {
            h16x8 pa = *(const h16x8*)&Ps[w * 16 * 72 + (lane & 15) * 72 + ks2 * 32 + (lane >> 4) * 8];
#pragma unroll
            for (int nt2 = 0; nt2 < 4; ++nt2) {
                h16x8 bv = *(const h16x8*)&Vs[(nt2 * 16 + (lane & 15)) * 72 + ks2 * 32 + (lane >> 4) * 8];
                acco[nt2] = __builtin_amdgcn_mfma_f32_16x16x32_f16(pa, bv, acco[nt2], 0, 0, 0);
            }
        }
    }
#pragma unroll
    for (int j = 0; j < 4; ++j) {
        const float inv = 1.0f / l[j];
        const size_t r = qrow0 + w * 16 + ((lane >> 4) << 2) + j;
#pragma unroll
        for (int nt2 = 0; nt2 < 4; ++nt2)
            Qb[r * 512 + col0 + nt2 * 16 + (lane & 15)] = (_Float16)(acco[nt2][j] * inv);
    }
}

// ---------------- poison fill ----------------
__global__ __launch_bounds__(256) void fill_poison(uint4* __restrict__ p, int n) {
    const uint4 v = {POISON, POISON, POISON, POISON};
    int i = blockIdx.x * 256 + threadIdx.x;
    const int st = gridDim.x * 256;
    for (; i < n; i += st) p[i] = v;
}

// ---------------- persistent single-layer RNN (256 blocks = 32 b x 8 slices) --------
// Barrier-free step. jq = tid>>4 (j quarter), kg = tid&15 (k fragment).
// Whh fp16 LDS-resident [64][512] row-major; read chunks l = 16*c8 + kg (kg in low
// bits -> uniform banks, zero conflicts). h published as packed 2xfp16 per u32 with
// poison sentinel; consumers gather their own 8 x b64 relaxed agent loads w/ retry.
// Reduction over kg via 4 rounds of shfl_xor width 16. No __syncthreads in the loop.
__global__ __launch_bounds__(256) void rnn_persist(const float* __restrict__ pre,
                                                   const _Float16* __restrict__ W16,
                                                   const float* __restrict__ bhh,
                                                   unsigned* __restrict__ hu) {
    __shared__ __align__(16) _Float16 Wl[64 * 512];   // 64 KB
    const int tid = threadIdx.x;
    const int b = blockIdx.x & 31;
    const int sl = blockIdx.x >> 5;
    const int jq = tid >> 4;          // 0..15
    const int kg = tid & 15;          // 0..15
    const int jbase = sl * 64;

    // stage Whh slice -> LDS fp16, row-major (linear; conflict-freedom comes from
    // the read-side chunk interleave, not a swizzle)
#pragma unroll
    for (int i = 0; i < 16; ++i) {
        const int e = tid + i * 256;
        const int row = e >> 6;
        const int l = e & 63;
        *(h16x8*)&Wl[row * 512 + l * 8] =
            *(const h16x8*)&W16[(size_t)(jbase + row) * 512 + l * 8];
    }
    // writer lanes (kg<2) handle the j-pair jbase + jq*4 + kg*2 + {0,1}
    const int jp = jq * 4 + (kg & 1) * 2;
    const float bj0 = bhh[jbase + jp];
    const float bj1 = bhh[jbase + jp + 1];
    __syncthreads();

    for (int t = 0; t < S; ++t) {
        // LDS weight reads: issued first; lgkmcnt independent of the vmcnt poll
        h16x8 w0[4], w1[4], w2[4], w3[4];
#pragma unroll
        for (int c8 = 0; c8 < 4; ++c8) {
            const int l8 = (16 * c8 + kg) * 8;
            w0[c8] = *(const h16x8*)&Wl[(jq * 4 + 0) * 512 + l8];
            w1[c8] = *(const h16x8*)&Wl[(jq * 4 + 1) * 512 + l8];
            w2[c8] = *(const h16x8*)&Wl[(jq * 4 + 2) * 512 + l8];
            w3[c8] = *(const h16x8*)&Wl[(jq * 4 + 3) * 512 + l8];
        }
        const float2 pv = *(const float2*)&pre[((size_t)t * 32 + b) * 512 + jbase + jp];
        float a0 = 0.f, a1 = 0.f, a2 = 0.f, a3 = 0.f;
        if (t > 0) {
            const unsigned long long* src =
                (const unsigned long long*)(hu + (size_t)(t - 1) * (B * H / 2) + b * 256);
            unsigned long long v[8];
            bool again = true;
            while (again) {
#pragma unroll
                for (int c8 = 0; c8 < 4; ++c8) {
                    const int u2 = (16 * c8 + kg) * 2;   // u64 index
                    v[c8 * 2 + 0] = __hip_atomic_load(src + u2, __ATOMIC_RELAXED,
                                                      __HIP_MEMORY_SCOPE_AGENT);
                    v[c8 * 2 + 1] = __hip_atomic_load(src + u2 + 1, __ATOMIC_RELAXED,
                                                      __HIP_MEMORY_SCOPE_AGENT);
                }
                again = false;
#pragma unroll
                for (int i = 0; i < 8; ++i) {
                    if ((unsigned)v[i] == POISON || (unsigned)(v[i] >> 32) == POISON)
                        again = true;
                }
                if (again) __builtin_amdgcn_s_sleep(1);
            }
#pragma unroll
            for (int c8 = 0; c8 < 4; ++c8) {
                h16x2 hpx[4];
                hpx[0] = asp((unsigned)v[c8 * 2 + 0]);
                hpx[1] = asp((unsigned)(v[c8 * 2 + 0] >> 32));
                hpx[2] = asp((unsigned)v[c8 * 2 + 1]);
                hpx[3] = asp((unsigned)(v[c8 * 2 + 1] >> 32));
#pragma unroll
                for (int q = 0; q < 4; ++q) {
                    a0 = dot2f(pr(w0[c8], q), hpx[q], a0);
                    a1 = dot2f(pr(w1[c8], q), hpx[q], a1);
                    a2 = dot2f(pr(w2[c8], q), hpx[q], a2);
                    a3 = dot2f(pr(w3[c8], q), hpx[q], a3);
                }
            }
        }
        // reduce across the 16 kg lanes (contiguous within the wave)
#pragma unroll
        for (int o = 1; o < 16; o <<= 1) {
            a0 += __shfl_xor(a0, o, 16);
            a1 += __shfl_xor(a1, o, 16);
            a2 += __shfl_xor(a2, o, 16);
            a3 += __shfl_xor(a3, o, 16);
        }
        if (kg < 2) {
            const float sa = (kg == 0) ? a0 : a2;
            const float sb = (kg == 0) ? a1 : a3;
            float s0 = sa + pv.x + bj0;
            float s1 = sb + pv.y + bj1;
            s0 = fminf(fmaxf(s0, -15.f), 15.f);
            s1 = fminf(fmaxf(s1, -15.f), 15.f);
            const float e0 = __expf(2.f * s0), e1 = __expf(2.f * s1);
            const float h0 = (e0 - 1.f) / (e0 + 1.f);
            const float h1 = (e1 - 1.f) / (e1 + 1.f);
            __hip_atomic_store(&hu[(size_t)t * (B * H / 2) + b * 256 + (jbase + jp) / 2],
                               pack2(h0, h1), __ATOMIC_RELAXED, __HIP_MEMORY_SCOPE_AGENT);
        }
        // no __syncthreads: all step state is wave-local
    }
}

// ---------------- final FC: out[b] = h1[511][b,:] . Wfc[0,:] + bfc[0] ----------------
__global__ __launch_bounds__(64) void fc_out(const _Float16* __restrict__ hh,
                                             const float* __restrict__ Wfc,
                                             const float* __restrict__ bfc,
                                             float* __restrict__ out) {
    int b = blockIdx.x;
    int t = threadIdx.x;
    float a = 0.f;
    for (int j = t; j < 512; j += 64) a += (float)hh[b * 512 + j] * Wfc[j];
#pragma unroll
    for (int o = 32; o; o >>= 1) a += __shfl_down(a, o, 64);
    if (t == 0) out[b] = a + bfc[0];
}

extern "C" void kernel_launch(void* const* d_in, const int* in_sizes, int n_in,
                              void* d_out, int out_size, void* d_ws, size_t ws_size,
                              hipStream_t stream) {
    const float* x   = (const float*)d_in[0];
    const float* Wq  = (const float*)d_in[1];
    const float* bq  = (const float*)d_in[2];
    const float* Wk  = (const float*)d_in[3];
    const float* bk  = (const float*)d_in[4];
    const float* Wv  = (const float*)d_in[5];
    const float* bv  = (const float*)d_in[6];
    const float* Wo  = (const float*)d_in[7];
    const float* bo  = (const float*)d_in[8];
    const float* Wih = (const float*)d_in[9];
    const float* bih = (const float*)d_in[10];
    const float* Whh = (const float*)d_in[11];
    const float* bhh = (const float*)d_in[12];
    const float* Wfc = (const float*)d_in[13];
    const float* bfc = (const float*)d_in[14];
    float* out = (float*)d_out;
    char* base = (char*)d_ws;

    // [0,16M):  x_f16 -> h0 packed-f16 slab (16MB)
    // [32,48M): Q_f16 -> ctx f16
    // [48,64M): K_f16 -> atten_out f16 -> h1 packed-f16 slab
    // [64,80M): Vt f16
    // [80,112M): pre f32 (pre0, then pre1)
    // [112,116M): 8 fp16 weight copies
    _Float16* xh   = (_Float16*)(base);
    unsigned* h0u  = (unsigned*)(base);
    _Float16* h0h  = (_Float16*)(base);
    _Float16* Qh   = (_Float16*)(base + ((size_t)32 << 20));
    _Float16* Kh   = (_Float16*)(base + ((size_t)48 << 20));
    unsigned* h1u  = (unsigned*)(base + ((size_t)48 << 20));
    _Float16* h1h  = (_Float16*)(base + ((size_t)48 << 20));
    _Float16* Vth  = (_Float16*)(base + ((size_t)64 << 20));
    float*    pre  = (float*)(base + ((size_t)80 << 20));
    _Float16* wgt  = (_Float16*)(base + ((size_t)112 << 20));
    const size_t WSZ = 512 * 512;

    cast_h<<<dim3(4096), dim3(256), 0, stream>>>(x, xh, (B * S * E) / 4);
    cast_h<<<dim3(256), dim3(256), 0, stream>>>(Wq, wgt + 0 * WSZ, WSZ / 4);
    cast_h<<<dim3(256), dim3(256), 0, stream>>>(Wk, wgt + 1 * WSZ, WSZ / 4);
    cast_h<<<dim3(256), dim3(256), 0, stream>>>(Wv, wgt + 2 * WSZ, WSZ / 4);
    cast_h<<<dim3(256), dim3(256), 0, stream>>>(Wo, wgt + 3 * WSZ, WSZ / 4);
    cast_h<<<dim3(256), dim3(256), 0, stream>>>(Wih, wgt + 4 * WSZ, WSZ / 4);
    cast_h<<<dim3(256), dim3(256), 0, stream>>>(Wih + WSZ, wgt + 5 * WSZ, WSZ / 4);
    cast_h<<<dim3(256), dim3(256), 0, stream>>>(Whh, wgt + 6 * WSZ, WSZ / 4);
    cast_h<<<dim3(256), dim3(256), 0, stream>>>(Whh + WSZ, wgt + 7 * WSZ, WSZ / 4);

    const dim3 gg(4, 128), blk(256);
    gemm_mfma<1><<<gg, blk, 0, stream>>>(xh, wgt + 0 * WSZ, bq, Qh, B * S, E, E);
    gemm_mfma<1><<<gg, blk, 0, stream>>>(xh, wgt + 1 * WSZ, bk, Kh, B * S, E, E);
    gemm_mfma<2><<<gg, blk, 0, stream>>>(xh, wgt + 2 * WSZ, bv, Vth, B * S, E, E);
    attn_mfma<<<dim3(B * NH * 8), blk, 0, stream>>>(Qh, Kh, Vth);
    gemm_mfma<1><<<gg, blk, 0, stream>>>(Qh, wgt + 3 * WSZ, bo, Kh, B * S, E, E);
    gemm_mfma<3><<<gg, blk, 0, stream>>>(Kh, wgt + 4 * WSZ, bih, pre, B * S, H, E);

    // layer 0 (h0 slab overwrites x_f16, already consumed)
    fill_poison<<<dim3(1024), blk, 0, stream>>>((uint4*)base, (16 << 20) / 16);
    rnn_persist<<<dim3(256), blk, 0, stream>>>(pre, wgt + 6 * WSZ, bhh, h0u);
    // layer-1 input projection: pre1 = h0 @ Wih1^T + bih1 (rows already t*32+b)
    gemm_mfma<0><<<gg, blk, 0, stream>>>(h0h, wgt + 5 * WSZ, bih + 512, pre, B * S, H, H);
    // layer 1 (h1 slab overwrites atten_out, already consumed)
    fill_poison<<<dim3(1024), blk, 0, stream>>>((uint4*)(base + ((size_t)48 << 20)),
                                                (16 << 20) / 16);
    rnn_persist<<<dim3(256), blk, 0, stream>>>(pre, wgt + 7 * WSZ, bhh + 512, h1u);
    fc_out<<<dim3(32), dim3(64), 0, stream>>>(h1h + (size_t)511 * B * H, Wfc, bfc, out);
}